// Round 3
// baseline (356.369 us; speedup 1.0000x reference)
//
#include <hip/hip_runtime.h>
#include <stdint.h>

// ImplicitRHMCSampler — fused single-kernel implementation for MI355X (gfx950).
//
// Design:
//  * grid 256 x 256 threads; 1 block/CU (144 KB LDS), 4 waves, 16 rows/wave.
//  * W (row-major) and W^T stored in LDS as fp8 e4m3, XOR-swizzled by row&15
//    at 8-byte-chunk granularity -> conflict-free ds_read_b64 fragments.
//  * All matmuls via v_mfma_f32_16x16x32_fp8_fp8 in transposed orientation
//    (D = Wcopy * state^T): A-frag = rows of W-copy, B-frag = rows of state,
//    both contiguous. Output: lane owns batch-row (lane&15), n in
//    {16*nt + 4*(lane>>4) + r} -> 4-consecutive-byte fp8 packs per tile.
//  * z, v carried fp32 in registers. softplus/sigmoid factors computed once
//    per step; NFX=8 loops collapsed (gradient frozen; z-loop refreshed at
//    midpoint). 6 MFMA-matmuls per leapfrog step, 37 total.
//  * Wave-synchronous LDS reuse: state writes and fragment reads are ordered
//    by an explicit lgkmcnt(0)+memory fence (TBAA would otherwise let hipcc
//    hoist the b64 reads above the b32 writes -> uninit fp8-NaN bytes).

typedef float floatx4 __attribute__((ext_vector_type(4)));

#define LDS_WRM   0        // W row-major, fp8, 64 KB
#define LDS_S     65536    // W^T row-major, fp8, 64 KB
#define LDS_STATE 131072   // + wave*4096, 16x256 fp8 state buffer per wave
#define LDS_TOTAL 147456

#define L2E 1.4426950408889634f
#define LN2 0.6931471805599453f

// gfx950: __builtin_amdgcn_logf computes log2 (see __clang_hip_math.h __log2f)
#define LOG2F(x) __builtin_amdgcn_logf(x)
#define EXP2F(x) __builtin_amdgcn_exp2f(x)
#define RCPF(x)  __builtin_amdgcn_rcpf(x)

// Order LDS stores (this wave) before subsequent LDS loads: compiler fence
// (memory clobber) + HW drain of outstanding DS ops.
#define LDS_FENCE() asm volatile("s_waitcnt lgkmcnt(0)" ::: "memory")

__device__ __forceinline__ uint32_t pkbf16(float a, float b) {
  uint32_t r;
  asm("v_cvt_pk_bf16_f32 %0, %1, %2" : "=v"(r) : "v"(a), "v"(b));
  return r;
}

// full matmul: acc[nt] = (Wcopy @ state^T) tile; ASET = aW or aS (per-kc LDS
// addresses incl. swizzle), aB = state-buffer addresses.
#define MM(ASET)                                                               \
  do {                                                                         \
    _Pragma("unroll") for (int kc_ = 0; kc_ < 8; ++kc_) {                      \
      long long bfrag_ =                                                       \
          *reinterpret_cast<const long long*>(smem + aB[kc_]);                 \
      _Pragma("unroll") for (int nt_ = 0; nt_ < 16; ++nt_) {                   \
        long long afrag_ = *reinterpret_cast<const long long*>(                \
            smem + (ASET)[kc_] + nt_ * 4096);                                  \
        acc[nt_] = __builtin_amdgcn_mfma_f32_16x16x32_fp8_fp8(                 \
            afrag_, bfrag_, kc_ ? acc[nt_] : ZERO4, 0, 0, 0);                  \
      }                                                                        \
    }                                                                          \
  } while (0)

__global__ void __launch_bounds__(256, 1)
rhmc_kernel(const float* __restrict__ z0, const float* __restrict__ v0,
            const float* __restrict__ Wg, const float* __restrict__ biasg,
            float* __restrict__ out) {
  extern __shared__ char smem[];
  const floatx4 ZERO4 = {0.f, 0.f, 0.f, 0.f};
  const int tid = threadIdx.x;
  const int blk = blockIdx.x;

  // ---- stage W row-major -> LDS fp8 (swizzled) ----
#pragma unroll 1
  for (int it = 0; it < 32; ++it) {
    int chunk = tid + it * 256;  // 8192 chunks of 8 elements
    int row = chunk >> 5;
    int c8 = chunk & 31;
    const float4* p = reinterpret_cast<const float4*>(Wg + row * 256 + c8 * 8);
    float4 x0 = p[0], x1 = p[1];
    int lo = __builtin_amdgcn_cvt_pk_fp8_f32(x0.x, x0.y, 0, false);
    lo = __builtin_amdgcn_cvt_pk_fp8_f32(x0.z, x0.w, lo, true);
    int hi = __builtin_amdgcn_cvt_pk_fp8_f32(x1.x, x1.y, 0, false);
    hi = __builtin_amdgcn_cvt_pk_fp8_f32(x1.z, x1.w, hi, true);
    int sw = (c8 ^ (row & 15)) << 3;
    *reinterpret_cast<int2*>(smem + LDS_WRM + row * 256 + sw) =
        make_int2(lo, hi);
  }
  // ---- stage S = W^T -> LDS fp8 (swizzled); column gather from L2-hot W ----
#pragma unroll 1
  for (int it = 0; it < 32; ++it) {
    int chunk = tid + it * 256;
    int n = chunk >> 5;
    int c8 = chunk & 31;
    float xs[8];
#pragma unroll
    for (int j = 0; j < 8; ++j) xs[j] = Wg[(c8 * 8 + j) * 256 + n];
    int lo = __builtin_amdgcn_cvt_pk_fp8_f32(xs[0], xs[1], 0, false);
    lo = __builtin_amdgcn_cvt_pk_fp8_f32(xs[2], xs[3], lo, true);
    int hi = __builtin_amdgcn_cvt_pk_fp8_f32(xs[4], xs[5], 0, false);
    hi = __builtin_amdgcn_cvt_pk_fp8_f32(xs[6], xs[7], hi, true);
    int sw = (c8 ^ (n & 15)) << 3;
    *reinterpret_cast<int2*>(smem + LDS_S + n * 256 + sw) = make_int2(lo, hi);
  }
  __syncthreads();  // only barrier in the kernel

  const int lane = tid & 63;
  const int wv = tid >> 6;
  const int l15 = lane & 15;
  const int g = lane >> 4;
  const int colb = l15 * 256;
  const int stateB = LDS_STATE + wv * 4096;
  const int m = blk * 64 + wv * 16 + l15;  // global batch row owned by lane

  // per-kc fragment addresses (swizzle folded in once)
  int aW[8], aS[8], aB[8];
#pragma unroll
  for (int kc = 0; kc < 8; ++kc) {
    int c8 = (((4 * kc + g) ^ l15) << 3);
    aW[kc] = LDS_WRM + colb + c8;
    aS[kc] = LDS_S + colb + c8;
    aB[kc] = stateB + colb + c8;
  }
  // state write addresses: lane writes 4 fp8 (r=0..3) at n=16t+4g per t
  int ws[16];
#pragma unroll
  for (int t = 0; t < 16; ++t)
    ws[t] = stateB + colb + ((((2 * t + (g >> 1)) ^ l15)) << 3) + (g & 1) * 4;

  // ---- load state: lane owns row m, n = 16t + 4g + r ----
  float z_[64], v_[64];
  {
    const float4* zr = reinterpret_cast<const float4*>(z0 + m * 256 + g * 4);
    const float4* vr = reinterpret_cast<const float4*>(v0 + m * 256 + g * 4);
#pragma unroll
    for (int t = 0; t < 16; ++t) {
      float4 a = zr[t * 4];
      float4 b = vr[t * 4];
      z_[t * 4 + 0] = a.x; z_[t * 4 + 1] = a.y;
      z_[t * 4 + 2] = a.z; z_[t * 4 + 3] = a.w;
      v_[t * 4 + 0] = b.x; v_[t * 4 + 1] = b.y;
      v_[t * 4 + 2] = b.z; v_[t * 4 + 3] = b.w;
    }
  }
  uint32_t bias_[32];
#pragma unroll
  for (int t = 0; t < 16; ++t) {
    const float* bp = biasg + t * 16 + g * 4;
    bias_[t * 2 + 0] = pkbf16(bp[0], bp[1]);
    bias_[t * 2 + 1] = pkbf16(bp[2], bp[3]);
  }

  floatx4 acc[16];
  uint32_t pq_[64];   // packed bf16 (p = 0.5*sigma(a), q = 0.5*sigma(a)/sp(a))
  uint32_t spa_[32];  // packed bf16 softplus(a) pairs
  uint32_t k0_[32];   // packed bf16 z-loop constant pairs

  // quantize + write 16x256 fp8 state rows (lane's 64 values, 16 b32 writes)
  auto writeState = [&](auto val) {
#pragma unroll
    for (int t = 0; t < 16; ++t) {
      int d = __builtin_amdgcn_cvt_pk_fp8_f32(val(t * 4 + 0), val(t * 4 + 1),
                                              0, false);
      d = __builtin_amdgcn_cvt_pk_fp8_f32(val(t * 4 + 2), val(t * 4 + 3), d,
                                          true);
      *reinterpret_cast<int*>(smem + ws[t]) = d;
    }
    LDS_FENCE();  // stores visible before the MM fragment reads
  };
  // from acc = z@W (pre-bias): p, q, sp(a)
  auto stats = [&]() {
#pragma unroll
    for (int nt = 0; nt < 16; ++nt) {
#pragma unroll
      for (int rr = 0; rr < 2; ++rr) {
        uint32_t bp = bias_[nt * 2 + rr];
        float sp2[2];
#pragma unroll
        for (int h = 0; h < 2; ++h) {
          float b = __uint_as_float(h ? (bp & 0xffff0000u) : (bp << 16));
          float a = acc[nt][rr * 2 + h] + b;
          float e = EXP2F(a * L2E);
          float onep = 1.0f + e;
          float r1 = RCPF(onep);
          float p = 0.5f * e * r1;
          float sp = LOG2F(onep) * LN2;
          sp = fmaxf(sp, 1e-12f);
          float q = p * RCPF(sp);
          pq_[nt * 4 + rr * 2 + h] = pkbf16(p, q);
          sp2[h] = sp;
        }
        spa_[nt * 2 + rr] = pkbf16(sp2[0], sp2[1]);
      }
    }
  };
  // u = p*vh^2 - q  (dH_dz integrand)
  auto uVal = [&](int e) {
    uint32_t pk = pq_[e];
    float p = __uint_as_float(pk << 16);
    float q = __uint_as_float(pk & 0xffff0000u);
    float vv = v_[e];
    return fmaf(p * vv, vv, -q);
  };

  // ---- initial stats at z0 ----
  writeState([&](int e) { return z_[e]; });
  MM(aS);
  stats();

#pragma unroll 1
  for (int step = 0; step < 6; ++step) {
    // A: v-loop collapsed: vh = v - 8*(gamma/2)*dH_dz(z, v)
    writeState(uVal);
    MM(aW);
#pragma unroll
    for (int nt = 0; nt < 16; ++nt)
#pragma unroll
      for (int r = 0; r < 4; ++r) v_[nt * 4 + r] -= 0.04f * acc[nt][r];

    // B: c = vh@W + bias -> w = 0.5*sigma(c)/sp(c)
    writeState([&](int e) { return v_[e]; });
    MM(aS);
    writeState([&](int e) {
      int nt = e >> 2, r = e & 3;
      uint32_t bp = bias_[nt * 2 + (r >> 1)];
      float b = __uint_as_float((r & 1) ? (bp & 0xffff0000u) : (bp << 16));
      float c = acc[nt][r] + b;
      float ee = EXP2F(c * L2E);
      float onep = 1.0f + ee;
      float sp = LOG2F(onep) * LN2;
      return 0.5f * ee * RCPF(onep * sp);
    });
    MM(aW);  // acc = r = w @ W^T

    // B2: first half of z-loop (frozen at a(z)): zn4 = z + 0.04*g0,
    //     k0 = 0.02*(g0 - r) with g0 = sp(a)*vh - r
#pragma unroll
    for (int nt = 0; nt < 16; ++nt)
#pragma unroll
      for (int rr = 0; rr < 2; ++rr) {
        uint32_t sppk = spa_[nt * 2 + rr];
        float k0h[2];
#pragma unroll
        for (int h = 0; h < 2; ++h) {
          int e = nt * 4 + rr * 2 + h;
          float sp = __uint_as_float(h ? (sppk & 0xffff0000u) : (sppk << 16));
          float A = sp * v_[e];
          float rv = acc[nt][rr * 2 + h];
          z_[e] += 0.04f * (A - rv);
          k0h[h] = 0.02f * (A - 2.0f * rv);
        }
        k0_[nt * 2 + rr] = pkbf16(k0h[0], k0h[1]);
      }

    // C1: midpoint refresh a(zn4), second half: zn8 = zn4 + k0 + 0.02*sp*vh
    writeState([&](int e) { return z_[e]; });
    MM(aS);
#pragma unroll
    for (int nt = 0; nt < 16; ++nt)
#pragma unroll
      for (int rr = 0; rr < 2; ++rr) {
        uint32_t bp = bias_[nt * 2 + rr];
        uint32_t kk = k0_[nt * 2 + rr];
#pragma unroll
        for (int h = 0; h < 2; ++h) {
          int e = nt * 4 + rr * 2 + h;
          float b = __uint_as_float(h ? (bp & 0xffff0000u) : (bp << 16));
          float a = acc[nt][rr * 2 + h] + b;
          float ee = EXP2F(a * L2E);
          float sp = LOG2F(1.0f + ee) * LN2;
          float k0v = __uint_as_float(h ? (kk & 0xffff0000u) : (kk << 16));
          z_[e] += k0v + 0.02f * sp * v_[e];
        }
      }

    // D: a(z_new) -> stats (also serves next step's entry)
    writeState([&](int e) { return z_[e]; });
    MM(aS);
    stats();

    // E: v_new = vh - (gamma/2)*dH_dz(z_new, vh)
    writeState(uVal);
    MM(aW);
#pragma unroll
    for (int nt = 0; nt < 16; ++nt)
#pragma unroll
      for (int r = 0; r < 4; ++r) v_[nt * 4 + r] -= 0.005f * acc[nt][r];
  }

  // ---- store (2, 16384, 256) fp32 ----
  float4* oz = reinterpret_cast<float4*>(out + m * 256 + g * 4);
  float4* ov = reinterpret_cast<float4*>(out + 16384 * 256 + m * 256 + g * 4);
#pragma unroll
  for (int t = 0; t < 16; ++t) {
    float4 a, b;
    a.x = z_[t * 4 + 0]; a.y = z_[t * 4 + 1];
    a.z = z_[t * 4 + 2]; a.w = z_[t * 4 + 3];
    b.x = v_[t * 4 + 0]; b.y = v_[t * 4 + 1];
    b.z = v_[t * 4 + 2]; b.w = v_[t * 4 + 3];
    oz[t * 4] = a;
    ov[t * 4] = b;
  }
}

extern "C" void kernel_launch(void* const* d_in, const int* in_sizes, int n_in,
                              void* d_out, int out_size, void* d_ws,
                              size_t ws_size, hipStream_t stream) {
  (void)in_sizes; (void)n_in; (void)d_ws; (void)ws_size; (void)out_size;
  const float* z0 = (const float*)d_in[0];
  const float* v0 = (const float*)d_in[1];
  const float* Wg = (const float*)d_in[2];
  const float* bg = (const float*)d_in[3];
  float* out = (float*)d_out;
  (void)hipFuncSetAttribute(reinterpret_cast<const void*>(rhmc_kernel),
                            hipFuncAttributeMaxDynamicSharedMemorySize,
                            LDS_TOTAL);
  rhmc_kernel<<<256, 256, LDS_TOTAL, stream>>>(z0, v0, Wg, bg, out);
}

// Round 4
// 143.630 us; speedup vs baseline: 2.4812x; 2.4812x over previous
//
#include <hip/hip_runtime.h>
#include <stdint.h>

// ImplicitRHMCSampler — fused single-kernel implementation for MI355X (gfx950).
//
// Round-3 restructure: kill register spilling (was ~390 live vs 256 cap ->
// ~280 MB scratch traffic). Wave-PAIR shares a 16-row state tile; each wave
// owns half the n-columns (8 of 16 MFMA n-tiles) -> per-lane state halves.
//  * grid 256 x 512 threads; 1 block/CU (160 KB LDS), 8 waves, 4 groups.
//  * W (row-major) and W^T in LDS as fp8 e4m3, XOR-swizzled per row&15.
//  * Ping-pong 16x256 fp8 state buffer per group; ONE __syncthreads per
//    phase orders partner-wave writes before full-k MFMA reads.
//  * v_mfma_f32_16x16x32_fp8_fp8, transposed orientation (D = Wcopy@state^T).
//  * 6 MFMA-matmul phases per leapfrog step + 1 initial = 37 total.

typedef float floatx4 __attribute__((ext_vector_type(4)));

#define LDS_WRM   0        // W row-major, fp8, 64 KB
#define LDS_S     65536    // W^T row-major, fp8, 64 KB
#define LDS_STATE 131072   // + group*8192 + parity*4096 : 16x256 fp8
#define LDS_TOTAL 163840   // exactly 160 KiB

#define L2E 1.4426950408889634f
#define LN2 0.6931471805599453f

// gfx950: __builtin_amdgcn_logf computes log2 (see __clang_hip_math.h __log2f)
#define LOG2F(x) __builtin_amdgcn_logf(x)
#define EXP2F(x) __builtin_amdgcn_exp2f(x)
#define RCPF(x)  __builtin_amdgcn_rcpf(x)

__device__ __forceinline__ uint32_t pkbf16(float a, float b) {
  uint32_t r;
  asm("v_cvt_pk_bf16_f32 %0, %1, %2" : "=v"(r) : "v"(a), "v"(b));
  return r;
}

// acc[nt] = (Wcopy @ state^T) tile slice for this wave's 8 n-tiles.
// ASET = aW or aS (base incl. nh*32768 + swizzle); PB = state parity (const).
#define MM(ASET, PB)                                                           \
  do {                                                                         \
    _Pragma("unroll") for (int kc_ = 0; kc_ < 8; ++kc_) {                      \
      long long bfrag_ = *reinterpret_cast<const long long*>(                  \
          smem + aB[kc_] + (PB) * 4096);                                       \
      _Pragma("unroll") for (int nt_ = 0; nt_ < 8; ++nt_) {                    \
        long long afrag_ = *reinterpret_cast<const long long*>(                \
            smem + (ASET)[kc_] + nt_ * 4096);                                  \
        acc[nt_] = __builtin_amdgcn_mfma_f32_16x16x32_fp8_fp8(                 \
            afrag_, bfrag_, kc_ ? acc[nt_] : ZERO4, 0, 0, 0);                  \
      }                                                                        \
    }                                                                          \
  } while (0)

__global__ void __launch_bounds__(512, 1)
rhmc_kernel(const float* __restrict__ z0, const float* __restrict__ v0,
            const float* __restrict__ Wg, const float* __restrict__ biasg,
            float* __restrict__ out) {
  extern __shared__ char smem[];
  const floatx4 ZERO4 = {0.f, 0.f, 0.f, 0.f};
  const int tid = threadIdx.x;
  const int blk = blockIdx.x;

  // ---- stage W row-major -> LDS fp8 (swizzled) ----
#pragma unroll 1
  for (int it = 0; it < 16; ++it) {
    int chunk = tid + it * 512;  // 8192 chunks of 8 elements
    int row = chunk >> 5;
    int c8 = chunk & 31;
    const float4* p = reinterpret_cast<const float4*>(Wg + row * 256 + c8 * 8);
    float4 x0 = p[0], x1 = p[1];
    int lo = __builtin_amdgcn_cvt_pk_fp8_f32(x0.x, x0.y, 0, false);
    lo = __builtin_amdgcn_cvt_pk_fp8_f32(x0.z, x0.w, lo, true);
    int hi = __builtin_amdgcn_cvt_pk_fp8_f32(x1.x, x1.y, 0, false);
    hi = __builtin_amdgcn_cvt_pk_fp8_f32(x1.z, x1.w, hi, true);
    int sw = (c8 ^ (row & 15)) << 3;
    *reinterpret_cast<int2*>(smem + LDS_WRM + row * 256 + sw) =
        make_int2(lo, hi);
  }
  // ---- stage S = W^T -> LDS fp8 (swizzled); column gather (L2-hot) ----
#pragma unroll 1
  for (int it = 0; it < 16; ++it) {
    int chunk = tid + it * 512;
    int n = chunk >> 5;
    int c8 = chunk & 31;
    float xs[8];
#pragma unroll
    for (int j = 0; j < 8; ++j) xs[j] = Wg[(c8 * 8 + j) * 256 + n];
    int lo = __builtin_amdgcn_cvt_pk_fp8_f32(xs[0], xs[1], 0, false);
    lo = __builtin_amdgcn_cvt_pk_fp8_f32(xs[2], xs[3], lo, true);
    int hi = __builtin_amdgcn_cvt_pk_fp8_f32(xs[4], xs[5], 0, false);
    hi = __builtin_amdgcn_cvt_pk_fp8_f32(xs[6], xs[7], hi, true);
    int sw = (c8 ^ (n & 15)) << 3;
    *reinterpret_cast<int2*>(smem + LDS_S + n * 256 + sw) = make_int2(lo, hi);
  }
  __syncthreads();

  const int lane = tid & 63;
  const int wv = tid >> 6;
  const int gp = wv >> 1;   // group of 2 waves sharing 16 rows
  const int nh = wv & 1;    // n-half owned by this wave
  const int l15 = lane & 15;
  const int g = lane >> 4;
  const int colb = l15 * 256;
  const int stateB = LDS_STATE + gp * 8192;  // parity added as const offset
  const int m = blk * 64 + gp * 16 + l15;    // global batch row of this lane

  // per-kc fragment addresses (swizzle folded in once)
  int aW[8], aS[8], aB[8];
#pragma unroll
  for (int kc = 0; kc < 8; ++kc) {
    int c8 = (((4 * kc + g) ^ l15) << 3);
    aW[kc] = LDS_WRM + nh * 32768 + colb + c8;
    aS[kc] = LDS_S + nh * 32768 + colb + c8;
    aB[kc] = stateB + colb + c8;
  }
  // state write addresses: lane writes 4 fp8 at n = 16*(8nh+t)+4g, r=0..3
  int ws[8];
#pragma unroll
  for (int t = 0; t < 8; ++t)
    ws[t] = stateB + colb +
            ((((2 * (8 * nh + t) + (g >> 1)) ^ l15)) << 3) + (g & 1) * 4;

  // ---- load state: lane owns row m, n = 128*nh + 16t + 4g + r ----
  float z_[32], v_[32];
  {
    const float4* zr =
        reinterpret_cast<const float4*>(z0 + m * 256 + nh * 128 + g * 4);
    const float4* vr =
        reinterpret_cast<const float4*>(v0 + m * 256 + nh * 128 + g * 4);
#pragma unroll
    for (int t = 0; t < 8; ++t) {
      float4 a = zr[t * 4];
      float4 b = vr[t * 4];
      z_[t * 4 + 0] = a.x; z_[t * 4 + 1] = a.y;
      z_[t * 4 + 2] = a.z; z_[t * 4 + 3] = a.w;
      v_[t * 4 + 0] = b.x; v_[t * 4 + 1] = b.y;
      v_[t * 4 + 2] = b.z; v_[t * 4 + 3] = b.w;
    }
  }
  uint32_t bias_[16];
#pragma unroll
  for (int t = 0; t < 8; ++t) {
    const float* bp = biasg + (8 * nh + t) * 16 + g * 4;
    bias_[t * 2 + 0] = pkbf16(bp[0], bp[1]);
    bias_[t * 2 + 1] = pkbf16(bp[2], bp[3]);
  }

  floatx4 acc[8];
  uint32_t pq_[32];   // packed bf16 (p = 0.5*sig(a), q = p/sp(a)) per element
  uint32_t spa_[16];  // packed bf16 softplus(a) pairs
  uint32_t k0_[16];   // packed bf16 z-loop constant pairs

  // quantize + write this wave's 32 values (its n-half of the 16x256 tile)
  auto writeState = [&](auto val, int PB) {
#pragma unroll
    for (int t = 0; t < 8; ++t) {
      int d = __builtin_amdgcn_cvt_pk_fp8_f32(val(t * 4 + 0), val(t * 4 + 1),
                                              0, false);
      d = __builtin_amdgcn_cvt_pk_fp8_f32(val(t * 4 + 2), val(t * 4 + 3), d,
                                          true);
      *reinterpret_cast<int*>(smem + ws[t] + PB * 4096) = d;
    }
  };
  // from acc = z@W (pre-bias): p, q, sp(a)
  auto stats = [&]() {
#pragma unroll
    for (int nt = 0; nt < 8; ++nt) {
#pragma unroll
      for (int rr = 0; rr < 2; ++rr) {
        uint32_t bp = bias_[nt * 2 + rr];
        float sp2[2];
#pragma unroll
        for (int h = 0; h < 2; ++h) {
          float b = __uint_as_float(h ? (bp & 0xffff0000u) : (bp << 16));
          float a = acc[nt][rr * 2 + h] + b;
          float e = EXP2F(a * L2E);
          float onep = 1.0f + e;
          float r1 = RCPF(onep);
          float p = 0.5f * e * r1;
          float sp = LOG2F(onep) * LN2;
          sp = fmaxf(sp, 1e-12f);
          float q = p * RCPF(sp);
          pq_[nt * 4 + rr * 2 + h] = pkbf16(p, q);
          sp2[h] = sp;
        }
        spa_[nt * 2 + rr] = pkbf16(sp2[0], sp2[1]);
      }
    }
  };
  // u = p*vh^2 - q  (dH_dz integrand)
  auto uVal = [&](int e) {
    uint32_t pk = pq_[e];
    float p = __uint_as_float(pk << 16);
    float q = __uint_as_float(pk & 0xffff0000u);
    float vv = v_[e];
    return fmaf(p * vv, vv, -q);
  };

  // ---- initial stats at z0 (parity 0) ----
  writeState([&](int e) { return z_[e]; }, 0);
  __syncthreads();
  MM(aS, 0);
  stats();

#pragma unroll 1
  for (int step = 0; step < 6; ++step) {
    // A (parity 1): v-loop collapsed: vh = v - 8*(gamma/2)*dH_dz(z, v)
    writeState(uVal, 1);
    __syncthreads();
    MM(aW, 1);
#pragma unroll
    for (int nt = 0; nt < 8; ++nt)
#pragma unroll
      for (int r = 0; r < 4; ++r) v_[nt * 4 + r] -= 0.04f * acc[nt][r];

    // B (parity 0): c = vh@W + bias -> w = 0.5*sigma(c)/sp(c)
    writeState([&](int e) { return v_[e]; }, 0);
    __syncthreads();
    MM(aS, 0);
    // B' (parity 1): acc -> w, then r = w @ W^T
    writeState(
        [&](int e) {
          int nt = e >> 2, r = e & 3;
          uint32_t bp = bias_[nt * 2 + (r >> 1)];
          float b = __uint_as_float((r & 1) ? (bp & 0xffff0000u) : (bp << 16));
          float c = acc[nt][r] + b;
          float ee = EXP2F(c * L2E);
          float onep = 1.0f + ee;
          float sp = LOG2F(onep) * LN2;
          return 0.5f * ee * RCPF(onep * sp);
        },
        1);
    __syncthreads();
    MM(aW, 1);

    // B2: first half of z-loop (frozen at a(z)): zn4 = z + 0.04*g0,
    //     k0 = 0.02*(g0 - r) with g0 = sp(a)*vh - r
#pragma unroll
    for (int nt = 0; nt < 8; ++nt)
#pragma unroll
      for (int rr = 0; rr < 2; ++rr) {
        uint32_t sppk = spa_[nt * 2 + rr];
        float k0h[2];
#pragma unroll
        for (int h = 0; h < 2; ++h) {
          int e = nt * 4 + rr * 2 + h;
          float sp = __uint_as_float(h ? (sppk & 0xffff0000u) : (sppk << 16));
          float A = sp * v_[e];
          float rv = acc[nt][rr * 2 + h];
          z_[e] += 0.04f * (A - rv);
          k0h[h] = 0.02f * (A - 2.0f * rv);
        }
        k0_[nt * 2 + rr] = pkbf16(k0h[0], k0h[1]);
      }

    // C1 (parity 0): midpoint refresh a(zn4); zn8 = zn4 + k0 + 0.02*sp*vh
    writeState([&](int e) { return z_[e]; }, 0);
    __syncthreads();
    MM(aS, 0);
#pragma unroll
    for (int nt = 0; nt < 8; ++nt)
#pragma unroll
      for (int rr = 0; rr < 2; ++rr) {
        uint32_t bp = bias_[nt * 2 + rr];
        uint32_t kk = k0_[nt * 2 + rr];
#pragma unroll
        for (int h = 0; h < 2; ++h) {
          int e = nt * 4 + rr * 2 + h;
          float b = __uint_as_float(h ? (bp & 0xffff0000u) : (bp << 16));
          float a = acc[nt][rr * 2 + h] + b;
          float ee = EXP2F(a * L2E);
          float sp = LOG2F(1.0f + ee) * LN2;
          float k0v = __uint_as_float(h ? (kk & 0xffff0000u) : (kk << 16));
          z_[e] += k0v + 0.02f * sp * v_[e];
        }
      }

    // D (parity 1): a(z_new) -> stats (also serves next step's entry)
    writeState([&](int e) { return z_[e]; }, 1);
    __syncthreads();
    MM(aS, 1);
    stats();

    // E (parity 0): v_new = vh - (gamma/2)*dH_dz(z_new, vh)
    writeState(uVal, 0);
    __syncthreads();
    MM(aW, 0);
#pragma unroll
    for (int nt = 0; nt < 8; ++nt)
#pragma unroll
      for (int r = 0; r < 4; ++r) v_[nt * 4 + r] -= 0.005f * acc[nt][r];
  }

  // ---- store (2, 16384, 256) fp32 ----
  float4* oz =
      reinterpret_cast<float4*>(out + m * 256 + nh * 128 + g * 4);
  float4* ov = reinterpret_cast<float4*>(out + 16384 * 256 + m * 256 +
                                         nh * 128 + g * 4);
#pragma unroll
  for (int t = 0; t < 8; ++t) {
    float4 a, b;
    a.x = z_[t * 4 + 0]; a.y = z_[t * 4 + 1];
    a.z = z_[t * 4 + 2]; a.w = z_[t * 4 + 3];
    b.x = v_[t * 4 + 0]; b.y = v_[t * 4 + 1];
    b.z = v_[t * 4 + 2]; b.w = v_[t * 4 + 3];
    oz[t * 4] = a;
    ov[t * 4] = b;
  }
}

extern "C" void kernel_launch(void* const* d_in, const int* in_sizes, int n_in,
                              void* d_out, int out_size, void* d_ws,
                              size_t ws_size, hipStream_t stream) {
  (void)in_sizes; (void)n_in; (void)d_ws; (void)ws_size; (void)out_size;
  const float* z0 = (const float*)d_in[0];
  const float* v0 = (const float*)d_in[1];
  const float* Wg = (const float*)d_in[2];
  const float* bg = (const float*)d_in[3];
  float* out = (float*)d_out;
  (void)hipFuncSetAttribute(reinterpret_cast<const void*>(rhmc_kernel),
                            hipFuncAttributeMaxDynamicSharedMemorySize,
                            LDS_TOTAL);
  rhmc_kernel<<<256, 512, LDS_TOTAL, stream>>>(z0, v0, Wg, bg, out);
}